// Round 5
// baseline (11481.198 us; speedup 1.0000x reference)
//
#include <hip/hip_runtime.h>
#include <hip/hip_bf16.h>

// GRU: B=128, T=1024, D_IN=512, H=1024. Output = final hidden state [128,1024] fp32.
//
// Round 9 (reverting the sc0 experiment; building on verified round-6):
//  - Tagged exchange: every published bf16-pair is packed with a 32-bit step
//    tag into one 64-bit word (single-copy-atomic relaxed agent load/store).
//    Consumers poll the DATA itself (tag match => valid) -- the separate
//    flag round-trip, publisher drain-before-flag, and post-publish barrier
//    are all gone. Common-case exchange = ONE L3 round trip.
//  - WAR safety: parity double-buffer. h[t] -> hx[(t+1)&1] tag t+1, read at
//    step t+1 from hx[(t+1)&1]; rh[t] -> rx[t&1] tag t+1, read same step.
//    Producer laps are impossible: h[t+1]-publish transitively follows all
//    peers' stage-A[t] (which consumed the buffer being overwritten).
//  - Cross-run tag staleness: hx+rx zeroed each launch; t=0 expects tag 0
//    (zeroed buffer = h0 = 0, correct).
//  - 5 barriers/step (was 7); no flags; x@W_h moved before the h-poll so
//    producers get extra slack.

#define BB   128
#define TT   1024
#define DIN  512
#define HD   1024

typedef short short8 __attribute__((ext_vector_type(8)));
typedef float f32x4 __attribute__((ext_vector_type(4)));
typedef unsigned long long ull;

// ws layout (bytes)
#define WT_OFF    16384
#define RT_OFF    (WT_OFF + 3*HD*DIN*2)
#define HX_OFF    (RT_OFF + 3*HD*HD*2)          // 2 bufs * 128 rows * 512 ull = 1 MB
#define RX_OFF    (HX_OFF + 2*BB*512*8)         // 1 MB
#define XBF_OFF   (RX_OFF + 2*BB*512*8)
#define XBF_BYTES ((size_t)BB*TT*DIN*2)

__device__ __forceinline__ unsigned short f2bf(float f) {
    unsigned u = __builtin_bit_cast(unsigned, f);
    u = (u + 0x7FFFu + ((u >> 16) & 1u)) >> 16;   // RNE
    return (unsigned short)u;
}

__device__ __forceinline__ ull pack4v(float4 v) {
    return (ull)f2bf(v.x) | ((ull)f2bf(v.y) << 16) |
           ((ull)f2bf(v.z) << 32) | ((ull)f2bf(v.w) << 48);
}

__device__ __forceinline__ short8 ld8(const unsigned short* p) {
    return *(const short8*)p;
}

__device__ __forceinline__ ull ald(const ull* p) {
    return __hip_atomic_load(p, __ATOMIC_RELAXED, __HIP_MEMORY_SCOPE_AGENT);
}
__device__ __forceinline__ void ast(ull* p, ull v) {
    __hip_atomic_store(p, v, __ATOMIC_RELAXED, __HIP_MEMORY_SCOPE_AGENT);
}

#define MFMA(A, B, C) __builtin_amdgcn_mfma_f32_16x16x32_bf16((A), (B), (C), 0, 0, 0)

// ---- phase 0a: transpose + bf16-convert weights ----------------------------
__global__ void pack_weights(const float* __restrict__ w0, const float* __restrict__ w1,
                             const float* __restrict__ w2, const float* __restrict__ r0,
                             const float* __restrict__ r1, const float* __restrict__ r2,
                             unsigned short* __restrict__ wt, unsigned short* __restrict__ rt) {
    int z = blockIdx.z;
    int K = (z < 3) ? DIN : HD;
    int kb = blockIdx.x * 32;
    if (kb >= K) return;
    int nb = blockIdx.y * 32;
    const float* src = (z == 0) ? w0 : (z == 1) ? w1 : (z == 2) ? w2
                     : (z == 3) ? r0 : (z == 4) ? r1 : r2;
    unsigned short* dst = (z < 3) ? (wt + (size_t)z * HD * DIN)
                                  : (rt + (size_t)(z - 3) * HD * HD);
    __shared__ float tile[32][33];
    int tx = threadIdx.x & 31, ty = threadIdx.x >> 5;
    for (int i = ty; i < 32; i += 8)
        tile[i][tx] = src[(size_t)(kb + i) * HD + nb + tx];
    __syncthreads();
    for (int i = ty; i < 32; i += 8)
        dst[(size_t)(nb + i) * K + kb + tx] = f2bf(tile[tx][i]);
}

// ---- phase 0b: bf16-convert x ----------------------------------------------
__global__ void pack_x(const float* __restrict__ x, unsigned short* __restrict__ xbf,
                       long long n4) {
    long long i = (long long)blockIdx.x * blockDim.x + threadIdx.x;
    long long stride = (long long)gridDim.x * blockDim.x;
    const float4* xv = (const float4*)x;
    ull* o = (ull*)xbf;
    for (; i < n4; i += stride) o[i] = pack4v(xv[i]);
}

// ---- persistent GRU kernel -------------------------------------------------
__launch_bounds__(512, 2)
__global__ void gru_persistent(const float* __restrict__ x,
                               const unsigned short* __restrict__ xbf,  // may be null
                               const float* __restrict__ Bz, const float* __restrict__ Br,
                               const float* __restrict__ Bh,
                               const unsigned short* __restrict__ WT,
                               const unsigned short* __restrict__ RT,
                               ull* __restrict__ hx,
                               ull* __restrict__ rx,
                               float* __restrict__ out) {
    const int g = blockIdx.x;
    const int group  = g & 7;            // likely XCD id (blockIdx % 8)
    const int member = g >> 3;           // 0..31 within group
    const int rowbase = group * 16;
    const int colbase = member * 32;
    const int tid  = threadIdx.x;
    const int w    = tid >> 6;
    const int lane = tid & 63;
    const int frow = lane & 15;
    const int fquad = lane >> 4;
    const int k0 = fquad * 8;

    // stage A roles: (gA: z/r, cA: col half, hA: K half)
    const int gA = (w >> 2) & 1;
    const int cA = (w >> 1) & 1;
    const int hA = w & 1;
    // phase-1 x@W_h roles (w < 4)
    const int cB = w & 1;
    const int xh = (w >> 1) & 1;

    __shared__ unsigned short xsh[16][520];
    __shared__ unsigned short hsh[16][1032];
    __shared__ float zbuf[16][36];
    __shared__ float rtmp[16][36];
    __shared__ float hstate[16][36];
    __shared__ float redA[2][2][4][64];
    __shared__ float redB[2][10][4][64];  // [col-half][0..7: rh K-eighths, 8..9: x halves]

    if (tid < 128) {
        int row = tid >> 3, c4 = tid & 7;
        *(float4*)&hstate[row][c4 * 4] = make_float4(0.f, 0.f, 0.f, 0.f);
    }

    // ---- weight preload into registers (unified VGPR/AGPR file) -----------
    short8 wAx[8], wAh[16], wB0[4], wB1[4], wBx[8];
    {
        const unsigned short* wcolA = WT + ((size_t)gA * HD + colbase + cA * 16 + frow) * DIN;
        const unsigned short* rcolA = RT + ((size_t)gA * HD + colbase + cA * 16 + frow) * HD;
        #pragma unroll
        for (int i = 0; i < 8; ++i)  wAx[i] = ld8(wcolA + (hA * 8 + i) * 32 + k0);
        #pragma unroll
        for (int i = 0; i < 16; ++i) wAh[i] = ld8(rcolA + (hA * 16 + i) * 32 + k0);

        const unsigned short* rcolB0 = RT + ((size_t)2 * HD + colbase + frow) * HD;
        const unsigned short* rcolB1 = RT + ((size_t)2 * HD + colbase + 16 + frow) * HD;
        #pragma unroll
        for (int i = 0; i < 4; ++i) wB0[i] = ld8(rcolB0 + (w * 4 + i) * 32 + k0);
        #pragma unroll
        for (int i = 0; i < 4; ++i) wB1[i] = ld8(rcolB1 + (w * 4 + i) * 32 + k0);

        if (w < 4) {
            const unsigned short* wcolB = WT + ((size_t)2 * HD + colbase + cB * 16 + frow) * DIN;
            #pragma unroll
            for (int i = 0; i < 8; ++i) wBx[i] = ld8(wcolB + (xh * 8 + i) * 32 + k0);
        }
    }
    const float bvA = (gA == 0 ? Bz : Br)[colbase + cA * 16 + frow];
    const float bvB = Bh[colbase + (w & 1) * 16 + frow];

#define STAGE_X(tt) do {                                                              \
        if (xbf) {                                                                    \
            const ull* xr = (const ull*)xbf;                                          \
            for (int i = tid; i < 2048; i += 512) {                                   \
                int row = i >> 7, c4 = i & 127;                                       \
                *(ull*)&xsh[row][c4 * 4] =                                            \
                    xr[((size_t)(rowbase + row) * TT + (tt)) * (DIN / 4) + c4];       \
            }                                                                         \
        } else {                                                                      \
            for (int i = tid; i < 2048; i += 512) {                                   \
                int row = i >> 7, c4 = i & 127;                                       \
                *(ull*)&xsh[row][c4 * 4] = pack4v(                                    \
                    ((const float4*)(x + ((size_t)(rowbase + row) * TT + (tt)) * DIN))[c4]); \
            }                                                                         \
        }                                                                             \
    } while (0)

    // x@W_{z,r} partials, loop-carried (computed for t+1 after the h publish)
    f32x4 xa0, xa1;
#define COMPUTE_XA() do {                                                             \
        f32x4 t0 = {0.f,0.f,0.f,0.f}, t1 = {0.f,0.f,0.f,0.f};                         \
        _Pragma("unroll")                                                             \
        for (int i = 0; i < 8; i += 2) {                                              \
            t0 = MFMA(ld8(&xsh[frow][(hA * 8 + i) * 32 + k0]), wAx[i], t0);           \
            t1 = MFMA(ld8(&xsh[frow][(hA * 8 + i + 1) * 32 + k0]), wAx[i + 1], t1);   \
        }                                                                             \
        xa0 = t0; xa1 = t1;                                                           \
    } while (0)

    // stage x[0] + its z/r partials
    STAGE_X(0);
    __syncthreads();
    COMPUTE_XA();

    for (int t = 0; t < TT; ++t) {
        // ---- phase 1 -------------------------------------------------------
        // x @ W_h partials first (no h dependence; gives producers slack)
        if (w < 4) {
            f32x4 b0 = {0.f,0.f,0.f,0.f}, b1 = {0.f,0.f,0.f,0.f};
            #pragma unroll
            for (int i = 0; i < 8; i += 2) {
                b0 = MFMA(ld8(&xsh[frow][(xh * 8 + i) * 32 + k0]), wBx[i], b0);
                b1 = MFMA(ld8(&xsh[frow][(xh * 8 + i + 1) * 32 + k0]), wBx[i + 1], b1);
            }
            #pragma unroll
            for (int r4 = 0; r4 < 4; ++r4) redB[cB][8 + xh][r4][lane] = b0[r4] + b1[r4];
        }
        // tagged h[t-1] read: thread tid owns ull-column tid (producer tid>>4),
        // rows rowbase..rowbase+15. tag == t (t=0: zeroed buffer, h0 = 0).
        {
            const unsigned need = (unsigned)t;
            const ull* hsrc = hx + ((size_t)(t & 1) * BB + rowbase) * 512 + tid;
            ull v[16];
            for (;;) {
                bool ok = true;
                #pragma unroll
                for (int j = 0; j < 16; ++j) v[j] = ald(hsrc + j * 512);
                #pragma unroll
                for (int j = 0; j < 16; ++j) ok &= ((unsigned)(v[j] >> 32) == need);
                if (ok) break;
                __builtin_amdgcn_s_sleep(1);
            }
            #pragma unroll
            for (int j = 0; j < 16; ++j)
                *(unsigned*)&hsh[j][2 * tid] = (unsigned)v[j];
        }
        __syncthreads();                                   // (A)

        // ---- stage A: z, r (h-K split evenly 16/16; x part precomputed) ----
        {
            f32x4 a0 = xa0, a1 = xa1;
            #pragma unroll
            for (int i = 0; i < 16; i += 2) {
                a0 = MFMA(ld8(&hsh[frow][(hA * 16 + i) * 32 + k0]), wAh[i], a0);
                a1 = MFMA(ld8(&hsh[frow][(hA * 16 + i + 1) * 32 + k0]), wAh[i + 1], a1);
            }
            if (hA == 1) {
                #pragma unroll
                for (int r4 = 0; r4 < 4; ++r4)
                    redA[gA][cA][r4][lane] = a0[r4] + a1[r4];
            }
            __syncthreads();                               // (B)
            if (hA == 0) {
                const int c = cA * 16 + frow;
                #pragma unroll
                for (int r4 = 0; r4 < 4; ++r4) {
                    int row = fquad * 4 + r4;
                    float pre = a0[r4] + a1[r4] + redA[gA][cA][r4][lane] + bvA;
                    float sg = 1.f / (1.f + __expf(-pre));
                    if (gA == 0) zbuf[row][c] = sg;
                    else         rtmp[row][c] = sg * hstate[row][c];
                }
            }
        }
        __syncthreads();                                   // (C)

        // ---- publish r*h tagged (fire-and-forget, no barrier/flag) --------
        {
            const ull tg = (ull)((unsigned)t + 1u) << 32;
            if (tid < 128) {
                int row = tid >> 3, q = tid & 7;
                ull* dst = rx + ((size_t)(t & 1) * BB + rowbase + row) * 512
                              + (colbase >> 1) + q * 2;
                const float* rp = &rtmp[row][q * 4];
                ast(dst,     (ull)f2bf(rp[0]) | ((ull)f2bf(rp[1]) << 16) | tg);
                ast(dst + 1, (ull)f2bf(rp[2]) | ((ull)f2bf(rp[3]) << 16) | tg);
            }
        }
        if (t + 1 < TT) {                                  // x[t+1]: overlaps peers' publishes
            STAGE_X(t + 1);
        }

        // ---- phase 2: tagged rh read (wave w <- members 4w..4w+3) ---------
        {
            const unsigned need = (unsigned)t + 1u;
            const ull* rsrc = rx + ((size_t)(t & 1) * BB + rowbase + frow) * 512
                                 + 64 * w + 4 * fquad;
            ull fr[4][4];
            for (;;) {
                bool ok = true;
                #pragma unroll
                for (int i = 0; i < 4; ++i)
                    #pragma unroll
                    for (int q = 0; q < 4; ++q) fr[i][q] = ald(rsrc + 16 * i + q);
                #pragma unroll
                for (int i = 0; i < 4; ++i)
                    #pragma unroll
                    for (int q = 0; q < 4; ++q)
                        ok &= ((unsigned)(fr[i][q] >> 32) == need);
                if (ok) break;
                __builtin_amdgcn_s_sleep(1);
            }
            f32x4 b0 = {0.f,0.f,0.f,0.f}, b1 = {0.f,0.f,0.f,0.f};
            #pragma unroll
            for (int i = 0; i < 4; ++i) {
                union { unsigned u[4]; short8 s; } mk;
                #pragma unroll
                for (int q = 0; q < 4; ++q) mk.u[q] = (unsigned)fr[i][q];
                b0 = MFMA(mk.s, wB0[i], b0);
                b1 = MFMA(mk.s, wB1[i], b1);
            }
            #pragma unroll
            for (int r4 = 0; r4 < 4; ++r4) {
                redB[0][w][r4][lane] = b0[r4];
                redB[1][w][r4][lane] = b1[r4];
            }
            __syncthreads();                               // (D)
            if (w < 2) {
                const int c = w * 16 + frow;
                #pragma unroll
                for (int r4 = 0; r4 < 4; ++r4) {
                    int row = fquad * 4 + r4;
                    float pre = bvB;
                    #pragma unroll
                    for (int s = 0; s < 10; ++s) pre += redB[w][s][r4][lane];
                    float e = __expf(2.f * pre);           // tanh = 1 - 2/(e+1)
                    float ht = 1.f - 2.f / (e + 1.f);
                    float zv = zbuf[row][c];
                    float ho = hstate[row][c];
                    hstate[row][c] = ho + zv * (ht - ho);
                }
            }
        }
        __syncthreads();                                   // (E)

        // ---- publish h tagged (fire-and-forget) ---------------------------
        if (t + 1 < TT) {
            const ull tg = (ull)((unsigned)t + 1u) << 32;
            if (tid < 128) {
                int row = tid >> 3, q = tid & 7;
                ull* dst = hx + ((size_t)((t + 1) & 1) * BB + rowbase + row) * 512
                              + (colbase >> 1) + q * 2;
                const float* hp = &hstate[row][q * 4];
                ast(dst,     (ull)f2bf(hp[0]) | ((ull)f2bf(hp[1]) << 16) | tg);
                ast(dst + 1, (ull)f2bf(hp[2]) | ((ull)f2bf(hp[3]) << 16) | tg);
            }
            // x@W_{z,r} partials for t+1: overlaps peers' h publishes
            COMPUTE_XA();
        }
    }

    if (tid < 128) {                                       // final output, fp32
        int row = tid >> 3, c4 = tid & 7;
        *(float4*)(out + (size_t)(rowbase + row) * HD + colbase + c4 * 4) =
            *(float4*)&hstate[row][c4 * 4];
    }
}

extern "C" void kernel_launch(void* const* d_in, const int* in_sizes, int n_in,
                              void* d_out, int out_size, void* d_ws, size_t ws_size,
                              hipStream_t stream) {
    const float* x  = (const float*)d_in[0];
    const float* Wz = (const float*)d_in[1];
    const float* Wr = (const float*)d_in[2];
    const float* Wh = (const float*)d_in[3];
    const float* Rz = (const float*)d_in[4];
    const float* Rr = (const float*)d_in[5];
    const float* Rh = (const float*)d_in[6];
    const float* Bz = (const float*)d_in[7];
    const float* Br = (const float*)d_in[8];
    const float* Bh = (const float*)d_in[9];

    char* ws = (char*)d_ws;
    unsigned short* WT = (unsigned short*)(ws + WT_OFF);
    unsigned short* RT = (unsigned short*)(ws + RT_OFF);
    ull*            HX = (ull*)(ws + HX_OFF);
    ull*            RX = (ull*)(ws + RX_OFF);

    const bool use_xbf = ws_size >= (size_t)XBF_OFF + XBF_BYTES;
    unsigned short* XBF = use_xbf ? (unsigned short*)(ws + XBF_OFF) : nullptr;

    // zero tag buffers (hx: t=0 reads tag 0 == h0 = 0; also kills cross-run tags)
    hipMemsetAsync(ws + HX_OFF, 0, (size_t)4 * BB * 512 * 8, stream);

    dim3 pgrid(HD / 32, HD / 32, 6);
    pack_weights<<<pgrid, 256, 0, stream>>>(Wz, Wr, Wh, Rz, Rr, Rh, WT, RT);
    if (use_xbf)
        pack_x<<<2048, 256, 0, stream>>>(x, XBF,
                                         (long long)((size_t)BB * TT * DIN / 4));

    gru_persistent<<<256, 512, 0, stream>>>(x, XBF, Bz, Br, Bh, WT, RT,
                                            HX, RX, (float*)d_out);
}